// Round 9
// baseline (612.280 us; speedup 1.0000x reference)
//
#include <hip/hip_runtime.h>
#include <cmath>

#define NPTS   1048576
#define NLVL   16
#define T      (1u << 19)
#define TMASK  (T - 1u)
#define P1     2654435761u
#define P2     805459861u

typedef float    v2f __attribute__((ext_vector_type(2)));
typedef float    v4f __attribute__((ext_vector_type(4)));
typedef _Float16 v2h __attribute__((ext_vector_type(2)));
typedef _Float16 v4h __attribute__((ext_vector_type(4)));

struct Corners { uint32_t h[8]; float wt[8]; };
struct RfArr   { float r[NLVL]; };

// Must match fp32 reference arithmetic exactly (same ops/order as the
// passing R1-R8 kernels).
__device__ __forceinline__ Corners mk_corners(float px, float py, float pz, float rf) {
    Corners cc;
    const float xs0 = px * rf, xs1 = py * rf, xs2 = pz * rf;
    const float f0 = floorf(xs0), f1 = floorf(xs1), f2 = floorf(xs2);
    const float w0 = xs0 - f0, w1 = xs1 - f1, w2 = xs2 - f2;
    const uint32_t i0 = (uint32_t)f0, i1 = (uint32_t)f1, i2 = (uint32_t)f2;
    const uint32_t A0 = i0,      A1 = i0 + 1u;
    const uint32_t B0 = i1 * P1, B1 = B0 + P1;
    const uint32_t C0 = i2 * P2, C1 = C0 + P2;
    cc.h[0] = (A0 ^ B0 ^ C0) & TMASK;  cc.h[1] = (A0 ^ B0 ^ C1) & TMASK;
    cc.h[2] = (A0 ^ B1 ^ C0) & TMASK;  cc.h[3] = (A0 ^ B1 ^ C1) & TMASK;
    cc.h[4] = (A1 ^ B0 ^ C0) & TMASK;  cc.h[5] = (A1 ^ B0 ^ C1) & TMASK;
    cc.h[6] = (A1 ^ B1 ^ C0) & TMASK;  cc.h[7] = (A1 ^ B1 ^ C1) & TMASK;
    const float u0 = 1.0f - w0, u1 = 1.0f - w1, u2 = 1.0f - w2;
    cc.wt[0] = (u0 * u1) * u2;  cc.wt[1] = (u0 * u1) * w2;
    cc.wt[2] = (u0 * w1) * u2;  cc.wt[3] = (u0 * w1) * w2;
    cc.wt[4] = (w0 * u1) * u2;  cc.wt[5] = (w0 * u1) * w2;
    cc.wt[6] = (w0 * w1) * u2;  cc.wt[7] = (w0 * w1) * w2;
    return cc;
}

// One launch for ALL levels: blockIdx.y = level (blocks dispatch x-fastest,
// so execution stays level-major -> per-level L2 behavior preserved).
// 2 adjacent points/thread (R6/R8-measured best MLP/TLP point), fp16 staging.
__global__ __launch_bounds__(256) void hashgrid_mega(
    const float* __restrict__ x,
    const float* __restrict__ table,
    _Float16* __restrict__ ws,
    RfArr rfa)
{
    const int   lvl = blockIdx.y;
    const float rf  = rfa.r[lvl];
    const float* __restrict__ tb  = table + ((size_t)lvl << 20);
    _Float16*  __restrict__   wsl = ws    + ((size_t)lvl << 21);

    const int t = blockIdx.x * 256 + threadIdx.x;   // 0 .. NPTS/2

    // contiguous 24B of x for points 2t, 2t+1 (8B-aligned)
    const v2f q0 = __builtin_nontemporal_load((const v2f*)(x + 6 * (size_t)t + 0));
    const v2f q1 = __builtin_nontemporal_load((const v2f*)(x + 6 * (size_t)t + 2));
    const v2f q2 = __builtin_nontemporal_load((const v2f*)(x + 6 * (size_t)t + 4));

    const Corners c0 = mk_corners(q0.x, q0.y, q1.x, rf);
    const Corners c1 = mk_corners(q1.y, q2.x, q2.y, rf);

    float a00 = 0.f, a01 = 0.f, a10 = 0.f, a11 = 0.f;
#pragma unroll
    for (int c = 0; c < 8; ++c) {
        const float2 g0 = *(const float2*)(tb + 2 * (size_t)c0.h[c]);
        const float2 g1 = *(const float2*)(tb + 2 * (size_t)c1.h[c]);
        a00 += c0.wt[c] * g0.x;  a01 += c0.wt[c] * g0.y;
        a10 += c1.wt[c] * g1.x;  a11 += c1.wt[c] * g1.y;
    }
    v4h r;
    r.x = (_Float16)a00;  r.y = (_Float16)a01;   // point 2t
    r.z = (_Float16)a10;  r.w = (_Float16)a11;   // point 2t+1
    __builtin_nontemporal_store(r, (v4h*)(wsl + 4 * (size_t)t));
}

// ws fp16 [16][N][2] -> out fp32 [N][32]. 2 points/thread: 16x 8B NT loads,
// 2x 128B cached stores (L2 merges into full lines).
__global__ __launch_bounds__(256) void hashgrid_transpose2(
    const _Float16* __restrict__ ws,
    float* __restrict__ out)
{
    const int t = blockIdx.x * 256 + threadIdx.x;   // 0 .. NPTS/2
    float acc0[2 * NLVL], acc1[2 * NLVL];
#pragma unroll
    for (int l = 0; l < NLVL; ++l) {
        const v4h g = __builtin_nontemporal_load(
            (const v4h*)(ws + ((size_t)l << 21) + 4 * (size_t)t));
        acc0[2 * l + 0] = (float)g.x;
        acc0[2 * l + 1] = (float)g.y;
        acc1[2 * l + 0] = (float)g.z;
        acc1[2 * l + 1] = (float)g.w;
    }
    v4f* o0 = (v4f*)(out + (size_t)(2 * t) * 32);
    v4f* o1 = (v4f*)(out + (size_t)(2 * t + 1) * 32);
#pragma unroll
    for (int k = 0; k < 8; ++k) {
        v4f v0; v0.x = acc0[4*k]; v0.y = acc0[4*k+1]; v0.z = acc0[4*k+2]; v0.w = acc0[4*k+3];
        o0[k] = v0;
    }
#pragma unroll
    for (int k = 0; k < 8; ++k) {
        v4f v1; v1.x = acc1[4*k]; v1.y = acc1[4*k+1]; v1.z = acc1[4*k+2]; v1.w = acc1[4*k+3];
        o1[k] = v1;
    }
}

// Fallback (no usable ws): one kernel per level, direct strided-out writes.
__global__ __launch_bounds__(256) void hashgrid_lvl_direct(
    const float* __restrict__ x,
    const float* __restrict__ tb,
    float* __restrict__ outl,
    float rf)
{
    const int n = blockIdx.x * 256 + threadIdx.x;
    const float px = __builtin_nontemporal_load(x + 3 * (size_t)n + 0);
    const float py = __builtin_nontemporal_load(x + 3 * (size_t)n + 1);
    const float pz = __builtin_nontemporal_load(x + 3 * (size_t)n + 2);
    const Corners cc = mk_corners(px, py, pz, rf);
    float a0 = 0.f, a1 = 0.f;
#pragma unroll
    for (int c = 0; c < 8; ++c) {
        const float2 g = *(const float2*)(tb + 2 * (size_t)cc.h[c]);
        a0 += cc.wt[c] * g.x;
        a1 += cc.wt[c] * g.y;
    }
    outl[(size_t)n * 32 + 0] = a0;
    outl[(size_t)n * 32 + 1] = a1;
}

extern "C" void kernel_launch(void* const* d_in, const int* in_sizes, int n_in,
                              void* d_out, int out_size, void* d_ws, size_t ws_size,
                              hipStream_t stream) {
    const float* x     = (const float*)d_in[0];
    const float* table = (const float*)d_in[1];
    float* out         = (float*)d_out;
    _Float16* ws       = (_Float16*)d_ws;

    // Reproduce Python's RESOLUTIONS bit-exactly using the same libm
    // (volatile fn pointers stop clang from folding/strength-reducing pow).
    double (*volatile p_log)(double)          = log;
    double (*volatile p_exp)(double)          = exp;
    double (*volatile p_pow)(double, double)  = pow;
    double (*volatile p_floor)(double)        = floor;

    const double b = p_exp((p_log(2048.0) - p_log(16.0)) / 15.0);
    RfArr rfa;
    for (int l = 0; l < NLVL; ++l)
        rfa.r[l] = (float)(int)p_floor(16.0 * p_pow(b, (double)l));

    const bool use_ws = ws_size >= (size_t)NLVL * NPTS * 2 * sizeof(_Float16);

    if (!use_ws) {
        for (int l = 0; l < NLVL; ++l)
            hashgrid_lvl_direct<<<NPTS / 256, 256, 0, stream>>>(
                x, table + ((size_t)l << 20), out + 2 * l, rfa.r[l]);
        return;
    }

    dim3 grid(NPTS / 512, NLVL);   // x: point-pairs, y: level (level-major dispatch)
    hashgrid_mega<<<grid, 256, 0, stream>>>(x, table, ws, rfa);
    hashgrid_transpose2<<<NPTS / 512, 256, 0, stream>>>(ws, out);
}

// Round 10
// 572.226 us; speedup vs baseline: 1.0700x; 1.0700x over previous
//
#include <hip/hip_runtime.h>
#include <cmath>

#define NPTS   1048576
#define NLVL   16
#define NLOW   5                 // levels 0..4: tables total ~2.6 MiB
#define T      (1u << 19)
#define TMASK  (T - 1u)
#define P1     2654435761u
#define P2     805459861u

typedef float    v2f __attribute__((ext_vector_type(2)));
typedef float    v4f __attribute__((ext_vector_type(4)));
typedef _Float16 v2h __attribute__((ext_vector_type(2)));
typedef _Float16 v4h __attribute__((ext_vector_type(4)));

struct Corners { uint32_t h[8]; float wt[8]; };
struct RfArr   { float r[NLVL]; };

// Must match fp32 reference arithmetic exactly (same ops/order as the
// passing R1-R9 kernels).
__device__ __forceinline__ Corners mk_corners(float px, float py, float pz, float rf) {
    Corners cc;
    const float xs0 = px * rf, xs1 = py * rf, xs2 = pz * rf;
    const float f0 = floorf(xs0), f1 = floorf(xs1), f2 = floorf(xs2);
    const float w0 = xs0 - f0, w1 = xs1 - f1, w2 = xs2 - f2;
    const uint32_t i0 = (uint32_t)f0, i1 = (uint32_t)f1, i2 = (uint32_t)f2;
    const uint32_t A0 = i0,      A1 = i0 + 1u;
    const uint32_t B0 = i1 * P1, B1 = B0 + P1;
    const uint32_t C0 = i2 * P2, C1 = C0 + P2;
    cc.h[0] = (A0 ^ B0 ^ C0) & TMASK;  cc.h[1] = (A0 ^ B0 ^ C1) & TMASK;
    cc.h[2] = (A0 ^ B1 ^ C0) & TMASK;  cc.h[3] = (A0 ^ B1 ^ C1) & TMASK;
    cc.h[4] = (A1 ^ B0 ^ C0) & TMASK;  cc.h[5] = (A1 ^ B0 ^ C1) & TMASK;
    cc.h[6] = (A1 ^ B1 ^ C0) & TMASK;  cc.h[7] = (A1 ^ B1 ^ C1) & TMASK;
    const float u0 = 1.0f - w0, u1 = 1.0f - w1, u2 = 1.0f - w2;
    cc.wt[0] = (u0 * u1) * u2;  cc.wt[1] = (u0 * u1) * w2;
    cc.wt[2] = (u0 * w1) * u2;  cc.wt[3] = (u0 * w1) * w2;
    cc.wt[4] = (w0 * u1) * u2;  cc.wt[5] = (w0 * u1) * w2;
    cc.wt[6] = (w0 * w1) * u2;  cc.wt[7] = (w0 * w1) * w2;
    return cc;
}

// Heavy level (full 4 MiB table): one level per launch (strict L2 residency,
// R9 showed co-residency regresses), 2 adjacent points/thread (R6/R8-best
// MLP point), fp16 staging: one 8B NT store for both points.
__global__ __launch_bounds__(256) void hashgrid_lvl2pt(
    const float* __restrict__ x,
    const float* __restrict__ tb,      // table + lvl*T*F
    _Float16* __restrict__ wsl,        // ws slice [N][2] fp16
    float rf)
{
    const int t = blockIdx.x * 256 + threadIdx.x;   // 0 .. NPTS/2

    const v2f q0 = __builtin_nontemporal_load((const v2f*)(x + 6 * (size_t)t + 0));
    const v2f q1 = __builtin_nontemporal_load((const v2f*)(x + 6 * (size_t)t + 2));
    const v2f q2 = __builtin_nontemporal_load((const v2f*)(x + 6 * (size_t)t + 4));

    const Corners c0 = mk_corners(q0.x, q0.y, q1.x, rf);
    const Corners c1 = mk_corners(q1.y, q2.x, q2.y, rf);

    float a00 = 0.f, a01 = 0.f, a10 = 0.f, a11 = 0.f;
#pragma unroll
    for (int c = 0; c < 8; ++c) {
        const float2 g0 = *(const float2*)(tb + 2 * (size_t)c0.h[c]);
        const float2 g1 = *(const float2*)(tb + 2 * (size_t)c1.h[c]);
        a00 += c0.wt[c] * g0.x;  a01 += c0.wt[c] * g0.y;
        a10 += c1.wt[c] * g1.x;  a11 += c1.wt[c] * g1.y;
    }
    v4h r;
    r.x = (_Float16)a00;  r.y = (_Float16)a01;   // point 2t
    r.z = (_Float16)a10;  r.w = (_Float16)a11;   // point 2t+1
    __builtin_nontemporal_store(r, (v4h*)(wsl + 4 * (size_t)t));
}

// All 5 low levels in ONE kernel: tables total 2.6 MiB (co-residency safe,
// gathers are L1/L2-hit latency), x read once instead of 5x, 5 launches -> 1.
__global__ __launch_bounds__(256) void hashgrid_low(
    const float* __restrict__ x,
    const float* __restrict__ table,
    _Float16* __restrict__ ws,
    float r0, float r1, float r2, float r3, float r4)
{
    const int n = blockIdx.x * 256 + threadIdx.x;
    const float px = __builtin_nontemporal_load(x + 3 * (size_t)n + 0);
    const float py = __builtin_nontemporal_load(x + 3 * (size_t)n + 1);
    const float pz = __builtin_nontemporal_load(x + 3 * (size_t)n + 2);

    const float rs[NLOW] = {r0, r1, r2, r3, r4};
#pragma unroll
    for (int l = 0; l < NLOW; ++l) {
        const Corners cc = mk_corners(px, py, pz, rs[l]);
        const float* tb = table + ((size_t)l << 20);
        float a0 = 0.f, a1 = 0.f;
#pragma unroll
        for (int c = 0; c < 8; ++c) {
            const float2 g = *(const float2*)(tb + 2 * (size_t)cc.h[c]);
            a0 += cc.wt[c] * g.x;
            a1 += cc.wt[c] * g.y;
        }
        v2h r; r.x = (_Float16)a0; r.y = (_Float16)a1;
        __builtin_nontemporal_store(r, (v2h*)(ws + ((size_t)l << 21) + 2 * (size_t)n));
    }
}

// ws fp16 [16][N][2] -> out fp32 [N][32]. 2 points/thread: 16x 8B NT loads,
// 2x 128B cached stores (L2 merges full lines). ~30 us measured (R9).
__global__ __launch_bounds__(256) void hashgrid_transpose2(
    const _Float16* __restrict__ ws,
    float* __restrict__ out)
{
    const int t = blockIdx.x * 256 + threadIdx.x;   // 0 .. NPTS/2
    float acc0[2 * NLVL], acc1[2 * NLVL];
#pragma unroll
    for (int l = 0; l < NLVL; ++l) {
        const v4h g = __builtin_nontemporal_load(
            (const v4h*)(ws + ((size_t)l << 21) + 4 * (size_t)t));
        acc0[2 * l + 0] = (float)g.x;
        acc0[2 * l + 1] = (float)g.y;
        acc1[2 * l + 0] = (float)g.z;
        acc1[2 * l + 1] = (float)g.w;
    }
    v4f* o0 = (v4f*)(out + (size_t)(2 * t) * 32);
    v4f* o1 = (v4f*)(out + (size_t)(2 * t + 1) * 32);
#pragma unroll
    for (int k = 0; k < 8; ++k) {
        v4f v0; v0.x = acc0[4*k]; v0.y = acc0[4*k+1]; v0.z = acc0[4*k+2]; v0.w = acc0[4*k+3];
        o0[k] = v0;
    }
#pragma unroll
    for (int k = 0; k < 8; ++k) {
        v4f v1; v1.x = acc1[4*k]; v1.y = acc1[4*k+1]; v1.z = acc1[4*k+2]; v1.w = acc1[4*k+3];
        o1[k] = v1;
    }
}

// Fallback (no usable ws): one kernel per level, direct strided-out writes.
__global__ __launch_bounds__(256) void hashgrid_lvl_direct(
    const float* __restrict__ x,
    const float* __restrict__ tb,
    float* __restrict__ outl,
    float rf)
{
    const int n = blockIdx.x * 256 + threadIdx.x;
    const float px = __builtin_nontemporal_load(x + 3 * (size_t)n + 0);
    const float py = __builtin_nontemporal_load(x + 3 * (size_t)n + 1);
    const float pz = __builtin_nontemporal_load(x + 3 * (size_t)n + 2);
    const Corners cc = mk_corners(px, py, pz, rf);
    float a0 = 0.f, a1 = 0.f;
#pragma unroll
    for (int c = 0; c < 8; ++c) {
        const float2 g = *(const float2*)(tb + 2 * (size_t)cc.h[c]);
        a0 += cc.wt[c] * g.x;
        a1 += cc.wt[c] * g.y;
    }
    outl[(size_t)n * 32 + 0] = a0;
    outl[(size_t)n * 32 + 1] = a1;
}

extern "C" void kernel_launch(void* const* d_in, const int* in_sizes, int n_in,
                              void* d_out, int out_size, void* d_ws, size_t ws_size,
                              hipStream_t stream) {
    const float* x     = (const float*)d_in[0];
    const float* table = (const float*)d_in[1];
    float* out         = (float*)d_out;
    _Float16* ws       = (_Float16*)d_ws;

    // Reproduce Python's RESOLUTIONS bit-exactly using the same libm
    // (volatile fn pointers stop clang from folding/strength-reducing pow).
    double (*volatile p_log)(double)          = log;
    double (*volatile p_exp)(double)          = exp;
    double (*volatile p_pow)(double, double)  = pow;
    double (*volatile p_floor)(double)        = floor;

    const double b = p_exp((p_log(2048.0) - p_log(16.0)) / 15.0);
    RfArr rfa;
    for (int l = 0; l < NLVL; ++l)
        rfa.r[l] = (float)(int)p_floor(16.0 * p_pow(b, (double)l));

    const bool use_ws = ws_size >= (size_t)NLVL * NPTS * 2 * sizeof(_Float16);

    if (!use_ws) {
        for (int l = 0; l < NLVL; ++l)
            hashgrid_lvl_direct<<<NPTS / 256, 256, 0, stream>>>(
                x, table + ((size_t)l << 20), out + 2 * l, rfa.r[l]);
        return;
    }

    // heavy levels: strict one-level-per-launch (L2 residency), long pole first
    for (int l = NLOW; l < NLVL; ++l) {
        hashgrid_lvl2pt<<<NPTS / 512, 256, 0, stream>>>(
            x, table + ((size_t)l << 20), ws + ((size_t)l << 21), rfa.r[l]);
    }
    // all low levels in one launch (tables co-resident trivially)
    hashgrid_low<<<NPTS / 256, 256, 0, stream>>>(
        x, table, ws, rfa.r[0], rfa.r[1], rfa.r[2], rfa.r[3], rfa.r[4]);
    // final transpose
    hashgrid_transpose2<<<NPTS / 512, 256, 0, stream>>>(ws, out);
}

// Round 11
// 550.248 us; speedup vs baseline: 1.1127x; 1.0399x over previous
//
#include <hip/hip_runtime.h>
#include <cmath>

#define NPTS   1048576
#define NLVL   16
#define NLOW   5                 // levels 0..4: tables total ~2.6 MiB
#define T      (1u << 19)
#define TMASK  (T - 1u)
#define P1     2654435761u
#define P2     805459861u

typedef float    v2f __attribute__((ext_vector_type(2)));
typedef float    v4f __attribute__((ext_vector_type(4)));
typedef _Float16 v2h __attribute__((ext_vector_type(2)));
typedef _Float16 v4h __attribute__((ext_vector_type(4)));

struct RfArr { float r[NLVL]; };

// Pair-merged encode: dim0 uses hash prime 1, so for even i0 the corners
// (0,b,c) and (1,b,c) are ADJACENT table entries (h^1) -> one aligned 16B
// load covers both (same 64B line). Odd-i0 lanes take one extra 8B gather
// per pair (exec-masked). Line-requests/point: 8 -> ~6 (-25%).
// Same gathered values & weight expressions as the passing R1-R10 kernels;
// accumulation order is pair-wise (reorder error ~1e-10, threshold 6e-6 slack).
__device__ __forceinline__ void encode_pt(
    const float* __restrict__ tb, float px, float py, float pz, float rf,
    float& ra0, float& ra1)
{
    const float xs0 = px * rf, xs1 = py * rf, xs2 = pz * rf;
    const float f0 = floorf(xs0), f1 = floorf(xs1), f2 = floorf(xs2);
    const float w0 = xs0 - f0, w1 = xs1 - f1, w2 = xs2 - f2;
    const uint32_t i0 = (uint32_t)f0, i1 = (uint32_t)f1, i2 = (uint32_t)f2;
    const uint32_t A0 = i0,      A1 = i0 + 1u;
    const uint32_t B0 = i1 * P1, B1 = B0 + P1;
    const uint32_t C0 = i2 * P2, C1 = C0 + P2;
    const bool odd = (i0 & 1u) != 0u;
    const float u0 = 1.0f - w0, u1 = 1.0f - w1, u2 = 1.0f - w2;
    const float wb[2] = {u1, w1};
    const float wc[2] = {u2, w2};

    float a0 = 0.f, a1 = 0.f;
#pragma unroll
    for (int b = 0; b < 2; ++b) {
#pragma unroll
        for (int c = 0; c < 2; ++c) {
            const uint32_t hBC = (b ? B1 : B0) ^ (c ? C1 : C0);
            const uint32_t h0  = (A0 ^ hBC) & TMASK;
            const uint32_t e   = h0 & ~1u;                 // even entry, 16B-aligned
            const v4f gq = *(const v4f*)(tb + 2 * (size_t)e);
            const bool hi = (h0 & 1u) != 0u;
            v2f g0, g1;
            g0.x = hi ? gq.z : gq.x;   g0.y = hi ? gq.w : gq.y;
            g1.x = hi ? gq.x : gq.z;   g1.y = hi ? gq.y : gq.w;  // valid when i0 even
            if (odd) {                                     // exec-masked extra gather
                const uint32_t h1 = (A1 ^ hBC) & TMASK;
                g1 = *(const v2f*)(tb + 2 * (size_t)h1);
            }
            const float wt0 = (u0 * wb[b]) * wc[c];
            const float wt1 = (w0 * wb[b]) * wc[c];
            a0 += wt0 * g0.x;  a1 += wt0 * g0.y;
            a0 += wt1 * g1.x;  a1 += wt1 * g1.y;
        }
    }
    ra0 = a0; ra1 = a1;
}

// 2 adjacent points/thread (R6/R8-best MLP/TLP point), one level per
// blockIdx.y slice. Heavy levels launch with gridDim.y==1 (strict L2
// residency, R9); low levels 0..4 launch together (tables co-fit in L2).
__global__ __launch_bounds__(256) void hashgrid_lvl(
    const float* __restrict__ x,
    const float* __restrict__ table,
    _Float16* __restrict__ ws,
    RfArr rfa, int lvl_base)
{
    const int   lvl = lvl_base + blockIdx.y;
    const float rf  = rfa.r[lvl];
    const float* __restrict__ tb  = table + ((size_t)lvl << 20);
    _Float16*  __restrict__   wsl = ws    + ((size_t)lvl << 21);

    const int t = blockIdx.x * 256 + threadIdx.x;   // 0 .. NPTS/2

    const v2f q0 = __builtin_nontemporal_load((const v2f*)(x + 6 * (size_t)t + 0));
    const v2f q1 = __builtin_nontemporal_load((const v2f*)(x + 6 * (size_t)t + 2));
    const v2f q2 = __builtin_nontemporal_load((const v2f*)(x + 6 * (size_t)t + 4));

    float a00, a01, a10, a11;
    encode_pt(tb, q0.x, q0.y, q1.x, rf, a00, a01);
    encode_pt(tb, q1.y, q2.x, q2.y, rf, a10, a11);

    v4h r;
    r.x = (_Float16)a00;  r.y = (_Float16)a01;   // point 2t
    r.z = (_Float16)a10;  r.w = (_Float16)a11;   // point 2t+1
    __builtin_nontemporal_store(r, (v4h*)(wsl + 4 * (size_t)t));
}

// ws fp16 [16][N][2] -> out fp32 [N][32]. 2 points/thread: 16x 8B NT loads,
// 2x 128B cached stores (L2 merges full lines). ~30 us measured (R9).
__global__ __launch_bounds__(256) void hashgrid_transpose2(
    const _Float16* __restrict__ ws,
    float* __restrict__ out)
{
    const int t = blockIdx.x * 256 + threadIdx.x;   // 0 .. NPTS/2
    float acc0[2 * NLVL], acc1[2 * NLVL];
#pragma unroll
    for (int l = 0; l < NLVL; ++l) {
        const v4h g = __builtin_nontemporal_load(
            (const v4h*)(ws + ((size_t)l << 21) + 4 * (size_t)t));
        acc0[2 * l + 0] = (float)g.x;
        acc0[2 * l + 1] = (float)g.y;
        acc1[2 * l + 0] = (float)g.z;
        acc1[2 * l + 1] = (float)g.w;
    }
    v4f* o0 = (v4f*)(out + (size_t)(2 * t) * 32);
    v4f* o1 = (v4f*)(out + (size_t)(2 * t + 1) * 32);
#pragma unroll
    for (int k = 0; k < 8; ++k) {
        v4f v0; v0.x = acc0[4*k]; v0.y = acc0[4*k+1]; v0.z = acc0[4*k+2]; v0.w = acc0[4*k+3];
        o0[k] = v0;
    }
#pragma unroll
    for (int k = 0; k < 8; ++k) {
        v4f v1; v1.x = acc1[4*k]; v1.y = acc1[4*k+1]; v1.z = acc1[4*k+2]; v1.w = acc1[4*k+3];
        o1[k] = v1;
    }
}

// Fallback (no usable ws): one kernel per level, direct strided-out writes.
__global__ __launch_bounds__(256) void hashgrid_lvl_direct(
    const float* __restrict__ x,
    const float* __restrict__ tb,
    float* __restrict__ outl,
    float rf)
{
    const int n = blockIdx.x * 256 + threadIdx.x;
    const float px = __builtin_nontemporal_load(x + 3 * (size_t)n + 0);
    const float py = __builtin_nontemporal_load(x + 3 * (size_t)n + 1);
    const float pz = __builtin_nontemporal_load(x + 3 * (size_t)n + 2);
    float a0, a1;
    encode_pt(tb, px, py, pz, rf, a0, a1);
    outl[(size_t)n * 32 + 0] = a0;
    outl[(size_t)n * 32 + 1] = a1;
}

extern "C" void kernel_launch(void* const* d_in, const int* in_sizes, int n_in,
                              void* d_out, int out_size, void* d_ws, size_t ws_size,
                              hipStream_t stream) {
    const float* x     = (const float*)d_in[0];
    const float* table = (const float*)d_in[1];
    float* out         = (float*)d_out;
    _Float16* ws       = (_Float16*)d_ws;

    // Reproduce Python's RESOLUTIONS bit-exactly using the same libm
    // (volatile fn pointers stop clang from folding/strength-reducing pow).
    double (*volatile p_log)(double)          = log;
    double (*volatile p_exp)(double)          = exp;
    double (*volatile p_pow)(double, double)  = pow;
    double (*volatile p_floor)(double)        = floor;

    const double b = p_exp((p_log(2048.0) - p_log(16.0)) / 15.0);
    RfArr rfa;
    for (int l = 0; l < NLVL; ++l)
        rfa.r[l] = (float)(int)p_floor(16.0 * p_pow(b, (double)l));

    const bool use_ws = ws_size >= (size_t)NLVL * NPTS * 2 * sizeof(_Float16);

    if (!use_ws) {
        for (int l = 0; l < NLVL; ++l)
            hashgrid_lvl_direct<<<NPTS / 256, 256, 0, stream>>>(
                x, table + ((size_t)l << 20), out + 2 * l, rfa.r[l]);
        return;
    }

    // heavy levels: strict one-level-per-launch (L2 residency), long pole first
    for (int l = NLOW; l < NLVL; ++l) {
        dim3 g(NPTS / 512, 1);
        hashgrid_lvl<<<g, 256, 0, stream>>>(x, table, ws, rfa, l);
    }
    // low levels 0..4 in one launch, parallel across blockIdx.y (tables
    // co-fit in L2; no per-thread level serialization — avoids R10's MLP loss)
    {
        dim3 g(NPTS / 512, NLOW);
        hashgrid_lvl<<<g, 256, 0, stream>>>(x, table, ws, rfa, 0);
    }
    hashgrid_transpose2<<<NPTS / 512, 256, 0, stream>>>(ws, out);
}

// Round 12
// 543.009 us; speedup vs baseline: 1.1276x; 1.0133x over previous
//
#include <hip/hip_runtime.h>
#include <cmath>

#define NPTS   1048576
#define NLVL   16
#define NLOW   5                 // levels 0..4: tables total ~2.6 MiB
#define T      (1u << 19)
#define TMASK  (T - 1u)
#define P1     2654435761u
#define P2     805459861u

typedef float    v2f __attribute__((ext_vector_type(2)));
typedef float    v4f __attribute__((ext_vector_type(4)));
typedef _Float16 v2h __attribute__((ext_vector_type(2)));
typedef _Float16 v4h __attribute__((ext_vector_type(4)));

struct RfArr { float r[NLVL]; };

// ---------- plain encode (minimum VALU, 8 gathers) — for L1/L2-hit levels ----
// Must match fp32 reference arithmetic exactly (same ops/order as R1-R11).
__device__ __forceinline__ void encode_plain(
    const float* __restrict__ tb, float px, float py, float pz, float rf,
    float& ra0, float& ra1)
{
    const float xs0 = px * rf, xs1 = py * rf, xs2 = pz * rf;
    const float f0 = floorf(xs0), f1 = floorf(xs1), f2 = floorf(xs2);
    const float w0 = xs0 - f0, w1 = xs1 - f1, w2 = xs2 - f2;
    const uint32_t i0 = (uint32_t)f0, i1 = (uint32_t)f1, i2 = (uint32_t)f2;
    const uint32_t A0 = i0,      A1 = i0 + 1u;
    const uint32_t B0 = i1 * P1, B1 = B0 + P1;
    const uint32_t C0 = i2 * P2, C1 = C0 + P2;
    const uint32_t h[8] = {
        (A0 ^ B0 ^ C0) & TMASK, (A0 ^ B0 ^ C1) & TMASK,
        (A0 ^ B1 ^ C0) & TMASK, (A0 ^ B1 ^ C1) & TMASK,
        (A1 ^ B0 ^ C0) & TMASK, (A1 ^ B0 ^ C1) & TMASK,
        (A1 ^ B1 ^ C0) & TMASK, (A1 ^ B1 ^ C1) & TMASK };
    const float u0 = 1.0f - w0, u1 = 1.0f - w1, u2 = 1.0f - w2;
    const float wt[8] = {
        (u0 * u1) * u2, (u0 * u1) * w2, (u0 * w1) * u2, (u0 * w1) * w2,
        (w0 * u1) * u2, (w0 * u1) * w2, (w0 * w1) * u2, (w0 * w1) * w2 };
    float a0 = 0.f, a1 = 0.f;
#pragma unroll
    for (int c = 0; c < 8; ++c) {
        const float2 g = *(const float2*)(tb + 2 * (size_t)h[c]);
        a0 += wt[c] * g.x;
        a1 += wt[c] * g.y;
    }
    ra0 = a0; ra1 = a1;
}

// ---------- pair-merged encode — for full-table (L1-miss) levels ----------
// dim0 hash prime is 1: even i0 -> corners (0,b,c),(1,b,c) are adjacent
// entries, one aligned 16B load covers both. Odd-i0 lanes take one masked
// extra 8B gather per pair. Pair-wise accumulation (reorder ~1e-10, safe).
__device__ __forceinline__ void encode_pair(
    const float* __restrict__ tb, float px, float py, float pz, float rf,
    float& ra0, float& ra1)
{
    const float xs0 = px * rf, xs1 = py * rf, xs2 = pz * rf;
    const float f0 = floorf(xs0), f1 = floorf(xs1), f2 = floorf(xs2);
    const float w0 = xs0 - f0, w1 = xs1 - f1, w2 = xs2 - f2;
    const uint32_t i0 = (uint32_t)f0, i1 = (uint32_t)f1, i2 = (uint32_t)f2;
    const uint32_t A0 = i0,      A1 = i0 + 1u;
    const uint32_t B0 = i1 * P1, B1 = B0 + P1;
    const uint32_t C0 = i2 * P2, C1 = C0 + P2;
    const bool odd = (i0 & 1u) != 0u;
    const float u0 = 1.0f - w0, u1 = 1.0f - w1, u2 = 1.0f - w2;
    const float wb[2] = {u1, w1};
    const float wc[2] = {u2, w2};

    float a0 = 0.f, a1 = 0.f;
#pragma unroll
    for (int b = 0; b < 2; ++b) {
#pragma unroll
        for (int c = 0; c < 2; ++c) {
            const uint32_t hBC = (b ? B1 : B0) ^ (c ? C1 : C0);
            const uint32_t h0  = (A0 ^ hBC) & TMASK;
            const uint32_t e   = h0 & ~1u;                 // 16B-aligned pair
            const v4f gq = *(const v4f*)(tb + 2 * (size_t)e);
            const bool hi = (h0 & 1u) != 0u;
            v2f g0, g1;
            g0.x = hi ? gq.z : gq.x;   g0.y = hi ? gq.w : gq.y;
            g1.x = hi ? gq.x : gq.z;   g1.y = hi ? gq.y : gq.w;  // valid when i0 even
            if (odd) {                                     // exec-masked extra gather
                const uint32_t h1 = (A1 ^ hBC) & TMASK;
                g1 = *(const v2f*)(tb + 2 * (size_t)h1);
            }
            const float wt0 = (u0 * wb[b]) * wc[c];
            const float wt1 = (w0 * wb[b]) * wc[c];
            a0 += wt0 * g0.x;  a1 += wt0 * g0.y;
            a0 += wt1 * g1.x;  a1 += wt1 * g1.y;
        }
    }
    ra0 = a0; ra1 = a1;
}

// Heavy level: one level per launch (strict L2 residency, R9), 2 adjacent
// points/thread (R6/R8-best), pair-merged encode, fp16 NT staging.
__global__ __launch_bounds__(256) void hashgrid_heavy(
    const float* __restrict__ x,
    const float* __restrict__ tb,      // table + lvl*T*F
    _Float16* __restrict__ wsl,        // ws slice [N][2] fp16
    float rf)
{
    const int t = blockIdx.x * 256 + threadIdx.x;   // 0 .. NPTS/2

    const v2f q0 = __builtin_nontemporal_load((const v2f*)(x + 6 * (size_t)t + 0));
    const v2f q1 = __builtin_nontemporal_load((const v2f*)(x + 6 * (size_t)t + 2));
    const v2f q2 = __builtin_nontemporal_load((const v2f*)(x + 6 * (size_t)t + 4));

    float a00, a01, a10, a11;
    encode_pair(tb, q0.x, q0.y, q1.x, rf, a00, a01);
    encode_pair(tb, q1.y, q2.x, q2.y, rf, a10, a11);

    v4h r;
    r.x = (_Float16)a00;  r.y = (_Float16)a01;
    r.z = (_Float16)a10;  r.w = (_Float16)a11;
    __builtin_nontemporal_store(r, (v4h*)(wsl + 4 * (size_t)t));
}

// Low levels 0..4 in ONE launch via blockIdx.y (tables co-fit in L2),
// PLAIN encode (cheap-gather regime: minimum VALU, no divergence),
// 1 point/thread (R8-proven).
__global__ __launch_bounds__(256) void hashgrid_low(
    const float* __restrict__ x,
    const float* __restrict__ table,
    _Float16* __restrict__ ws,
    RfArr rfa)
{
    const int   lvl = blockIdx.y;
    const float rf  = rfa.r[lvl];
    const float* __restrict__ tb  = table + ((size_t)lvl << 20);
    _Float16*  __restrict__   wsl = ws    + ((size_t)lvl << 21);

    const int n = blockIdx.x * 256 + threadIdx.x;
    const float px = __builtin_nontemporal_load(x + 3 * (size_t)n + 0);
    const float py = __builtin_nontemporal_load(x + 3 * (size_t)n + 1);
    const float pz = __builtin_nontemporal_load(x + 3 * (size_t)n + 2);

    float a0, a1;
    encode_plain(tb, px, py, pz, rf, a0, a1);

    v2h r; r.x = (_Float16)a0; r.y = (_Float16)a1;
    __builtin_nontemporal_store(r, (v2h*)(wsl + 2 * (size_t)n));
}

// ws fp16 [16][N][2] -> out fp32 [N][32]. 2 points/thread: 16x 8B NT loads,
// 2x 128B cached stores (L2 merges full lines). ~30 us measured (R9).
__global__ __launch_bounds__(256) void hashgrid_transpose2(
    const _Float16* __restrict__ ws,
    float* __restrict__ out)
{
    const int t = blockIdx.x * 256 + threadIdx.x;   // 0 .. NPTS/2
    float acc0[2 * NLVL], acc1[2 * NLVL];
#pragma unroll
    for (int l = 0; l < NLVL; ++l) {
        const v4h g = __builtin_nontemporal_load(
            (const v4h*)(ws + ((size_t)l << 21) + 4 * (size_t)t));
        acc0[2 * l + 0] = (float)g.x;
        acc0[2 * l + 1] = (float)g.y;
        acc1[2 * l + 0] = (float)g.z;
        acc1[2 * l + 1] = (float)g.w;
    }
    v4f* o0 = (v4f*)(out + (size_t)(2 * t) * 32);
    v4f* o1 = (v4f*)(out + (size_t)(2 * t + 1) * 32);
#pragma unroll
    for (int k = 0; k < 8; ++k) {
        v4f v0; v0.x = acc0[4*k]; v0.y = acc0[4*k+1]; v0.z = acc0[4*k+2]; v0.w = acc0[4*k+3];
        o0[k] = v0;
    }
#pragma unroll
    for (int k = 0; k < 8; ++k) {
        v4f v1; v1.x = acc1[4*k]; v1.y = acc1[4*k+1]; v1.z = acc1[4*k+2]; v1.w = acc1[4*k+3];
        o1[k] = v1;
    }
}

// Fallback (no usable ws): one kernel per level, direct strided-out writes.
__global__ __launch_bounds__(256) void hashgrid_lvl_direct(
    const float* __restrict__ x,
    const float* __restrict__ tb,
    float* __restrict__ outl,
    float rf)
{
    const int n = blockIdx.x * 256 + threadIdx.x;
    const float px = __builtin_nontemporal_load(x + 3 * (size_t)n + 0);
    const float py = __builtin_nontemporal_load(x + 3 * (size_t)n + 1);
    const float pz = __builtin_nontemporal_load(x + 3 * (size_t)n + 2);
    float a0, a1;
    encode_plain(tb, px, py, pz, rf, a0, a1);
    outl[(size_t)n * 32 + 0] = a0;
    outl[(size_t)n * 32 + 1] = a1;
}

extern "C" void kernel_launch(void* const* d_in, const int* in_sizes, int n_in,
                              void* d_out, int out_size, void* d_ws, size_t ws_size,
                              hipStream_t stream) {
    const float* x     = (const float*)d_in[0];
    const float* table = (const float*)d_in[1];
    float* out         = (float*)d_out;
    _Float16* ws       = (_Float16*)d_ws;

    // Reproduce Python's RESOLUTIONS bit-exactly using the same libm
    // (volatile fn pointers stop clang from folding/strength-reducing pow).
    double (*volatile p_log)(double)          = log;
    double (*volatile p_exp)(double)          = exp;
    double (*volatile p_pow)(double, double)  = pow;
    double (*volatile p_floor)(double)        = floor;

    const double b = p_exp((p_log(2048.0) - p_log(16.0)) / 15.0);
    RfArr rfa;
    for (int l = 0; l < NLVL; ++l)
        rfa.r[l] = (float)(int)p_floor(16.0 * p_pow(b, (double)l));

    const bool use_ws = ws_size >= (size_t)NLVL * NPTS * 2 * sizeof(_Float16);

    if (!use_ws) {
        for (int l = 0; l < NLVL; ++l)
            hashgrid_lvl_direct<<<NPTS / 256, 256, 0, stream>>>(
                x, table + ((size_t)l << 20), out + 2 * l, rfa.r[l]);
        return;
    }

    // heavy levels: strict one-level-per-launch (L2 residency), long pole first
    for (int l = NLOW; l < NLVL; ++l) {
        hashgrid_heavy<<<NPTS / 512, 256, 0, stream>>>(
            x, table + ((size_t)l << 20), ws + ((size_t)l << 21), rfa.r[l]);
    }
    // low levels 0..4: one launch, parallel across blockIdx.y, plain encode
    {
        dim3 g(NPTS / 256, NLOW);
        hashgrid_low<<<g, 256, 0, stream>>>(x, table, ws, rfa);
    }
    hashgrid_transpose2<<<NPTS / 512, 256, 0, stream>>>(ws, out);
}